// Round 1
// baseline (26.454 us; speedup 1.0000x reference)
//
#include <hip/hip_runtime.h>
#include <hip/hip_bf16.h>

// out[b] = W00 * (1/R) * sum_i | prod_w cos((x[b,w] - x_ref[i,w])/2) | + b0
// Identity: cos((x-y)/2) = cos(x/2)cos(y/2) + sin(x/2)sin(y/2)
// -> precompute per-side sin/cos, inner loop is pure FMA/mul (no transcendentals).

constexpr int B_TOT = 8192;
constexpr int R_TOT = 4096;
constexpr int NTH   = 256;            // threads per block (pair kernel)
constexpr int TB    = 4;              // batch rows per thread
constexpr int BB    = NTH * TB;       // 1024 batch rows per block
constexpr int RCHUNK = 64;            // refs per block
constexpr int NRC   = R_TOT / RCHUNK; // 64 r-chunks

__global__ void prep_trig(const float* __restrict__ x,
                          float* __restrict__ cx,
                          float* __restrict__ sx, int n) {
    int i = blockIdx.x * blockDim.x + threadIdx.x;
    if (i < n) {
        float s, c;
        sincosf(0.5f * x[i], &s, &c);
        cx[i] = c;
        sx[i] = s;
    }
}

__global__ __launch_bounds__(NTH) void pair_kernel(
        const float* __restrict__ x_ref,
        const float* __restrict__ cx,
        const float* __restrict__ sx,
        float* __restrict__ part) {
    __shared__ float4 s_cy[RCHUNK];
    __shared__ float4 s_sy[RCHUNK];
    const int t = threadIdx.x;
    const int bbase = blockIdx.x * BB;
    const int rbase = blockIdx.y * RCHUNK;

    // Stage ref-side trig: 256 threads -> exactly 64 refs x 4 wires
    {
        int i = t >> 2, w = t & 3;
        float v = 0.5f * x_ref[(rbase + i) * 4 + w];
        float s, c;
        sincosf(v, &s, &c);
        reinterpret_cast<float*>(&s_cy[i])[w] = c;
        reinterpret_cast<float*>(&s_sy[i])[w] = s;
    }
    __syncthreads();

    float4 cxr[TB], sxr[TB];
    int bs[TB];
#pragma unroll
    for (int k = 0; k < TB; ++k) {
        bs[k] = bbase + t + k * NTH;
        cxr[k] = reinterpret_cast<const float4*>(cx)[bs[k]];
        sxr[k] = reinterpret_cast<const float4*>(sx)[bs[k]];
    }
    float acc[TB] = {0.f, 0.f, 0.f, 0.f};

#pragma unroll 4
    for (int i = 0; i < RCHUNK; ++i) {
        float4 cy = s_cy[i];
        float4 sy = s_sy[i];
#pragma unroll
        for (int k = 0; k < TB; ++k) {
            float t0 = cxr[k].x * cy.x + sxr[k].x * sy.x;
            float t1 = cxr[k].y * cy.y + sxr[k].y * sy.y;
            float t2 = cxr[k].z * cy.z + sxr[k].z * sy.z;
            float t3 = cxr[k].w * cy.w + sxr[k].w * sy.w;
            acc[k] += fabsf((t0 * t1) * (t2 * t3));
        }
    }

#pragma unroll
    for (int k = 0; k < TB; ++k)
        part[blockIdx.y * B_TOT + bs[k]] = acc[k];
}

__global__ void finish_kernel(const float* __restrict__ part,
                              const float* __restrict__ W,
                              const float* __restrict__ bias,
                              float* __restrict__ out) {
    int b = blockIdx.x * blockDim.x + threadIdx.x;
    if (b >= B_TOT) return;
    float s = 0.f;
#pragma unroll 8
    for (int j = 0; j < NRC; ++j) s += part[j * B_TOT + b];
    out[b] = s * (1.0f / R_TOT) * W[0] + bias[0];
}

extern "C" void kernel_launch(void* const* d_in, const int* in_sizes, int n_in,
                              void* d_out, int out_size, void* d_ws, size_t ws_size,
                              hipStream_t stream) {
    const float* x     = (const float*)d_in[0];  // (B, 4)
    const float* x_ref = (const float*)d_in[1];  // (R, 4)
    const float* W     = (const float*)d_in[2];  // (1, 1)
    const float* bias  = (const float*)d_in[3];  // (1,)
    float* out = (float*)d_out;                  // (B, 1)

    float* cx   = (float*)d_ws;                  // B*4 floats
    float* sx   = cx + B_TOT * 4;                // B*4 floats
    float* part = sx + B_TOT * 4;                // NRC * B floats

    prep_trig<<<(B_TOT * 4 + 255) / 256, 256, 0, stream>>>(x, cx, sx, B_TOT * 4);

    dim3 grid(B_TOT / BB, NRC);
    pair_kernel<<<grid, NTH, 0, stream>>>(x_ref, cx, sx, part);

    finish_kernel<<<(B_TOT + 255) / 256, 256, 0, stream>>>(part, W, bias, out);
}

// Round 2
// 14.781 us; speedup vs baseline: 1.7897x; 1.7897x over previous
//
#include <hip/hip_runtime.h>
#include <hip/hip_bf16.h>

// out[b] = W00 * (1/R) * sum_i | prod_w cos((x[b,w]-x_ref[i,w])/2) | + b0
//
// Identity: prod_{w=0..3} cos(a_w) = (1/8) * sum_{s in {+-1}^3} cos(a0 + s1*a1 + s2*a2 + s3*a3)
// With a_w = (x_w - y_w)/2 and g_s(h) = h0 + s1*h1 + s2*h2 + s3*h3 (h = x/2):
//   prod = (1/8) * sum_s [ cos(g_s^x)cos(g_s^y) + sin(g_s^x)sin(g_s^y) ]
//        = (1/8) * dot16( U_row(x), V_row(y) )
// where U_row = [cos g_0..g_7, sin g_0..g_7]  (16 bf16).
// => k-matrix = (1/8)|U @ V^T| : an (8192 x 4096, K=16) bf16 MFMA GEMM with
//    fused abs + row-mean epilogue. K-permutation of fragments cancels because
//    both operands use the same storage layout (symmetric A/B lane->k maps).

typedef __attribute__((ext_vector_type(8)))  short bf16x8;
typedef __attribute__((ext_vector_type(16))) float f32x16;

constexpr int B_TOT = 8192;
constexpr int R_TOT = 4096;
constexpr int NW    = 8;                    // waves per block (main kernel)
constexpr int NT    = (R_TOT / 32) / NW;    // col-tiles per wave = 16

static __device__ inline ushort f2bf(float f) {
    // round-to-nearest-even f32 -> bf16 (inputs are sin/cos: no NaN/Inf)
    unsigned u = __float_as_uint(f);
    return (ushort)((u + 0x7FFFu + ((u >> 16) & 1u)) >> 16);
}

// One thread per (row, sign-combo): rows 0..8191 -> U from x, 8192..12287 -> V from x_ref.
__global__ __launch_bounds__(256) void prep_kernel(const float* __restrict__ x,
                                                   const float* __restrict__ xr,
                                                   ushort* __restrict__ U,
                                                   ushort* __restrict__ V) {
    int tid = blockIdx.x * blockDim.x + threadIdx.x;   // 98304 total
    int row = tid >> 3;
    int c   = tid & 7;
    float4 h;
    ushort* dst;
    if (row < B_TOT) {
        h = reinterpret_cast<const float4*>(x)[row];
        dst = U + row * 16;
    } else {
        h = reinterpret_cast<const float4*>(xr)[row - B_TOT];
        dst = V + (row - B_TOT) * 16;
    }
    float g = 0.5f * (h.x + ((c & 1) ? -h.y : h.y)
                          + ((c & 2) ? -h.z : h.z)
                          + ((c & 4) ? -h.w : h.w));
    float s, co;
    sincosf(g, &s, &co);
    dst[c]     = f2bf(co);
    dst[8 + c] = f2bf(s);
}

__global__ __launch_bounds__(512) void pair_mfma(const ushort* __restrict__ U,
                                                 const ushort* __restrict__ V,
                                                 const float* __restrict__ Wm,
                                                 const float* __restrict__ bias,
                                                 float* __restrict__ out) {
    __shared__ float sRed[NW][32];
    const int l    = threadIdx.x & 63;
    const int w    = threadIdx.x >> 6;
    const int rs   = blockIdx.x;          // row stripe: rows rs*32 .. rs*32+31
    const int colw = l & 31;
    const int half = l >> 5;

    // A fragment: rows rs*32+colw, k-positions half*8..half*8+7 (any consistent
    // k-permutation is fine — see header comment).
    bf16x8 afrag = *reinterpret_cast<const bf16x8*>(U + (rs * 32 + colw) * 16 + half * 8);

    // B fragment base for this lane: col = tile*32 + colw, same k-half.
    const ushort* vb = V + colw * 16 + half * 8;
    const int t0 = w * NT;

    f32x16 zero;
    f32x16 rowacc;
#pragma unroll
    for (int r = 0; r < 16; ++r) { zero[r] = 0.0f; rowacc[r] = 0.0f; }

    bf16x8 bcur = *reinterpret_cast<const bf16x8*>(vb + (size_t)t0 * 512);
    f32x16 cprev = __builtin_amdgcn_mfma_f32_32x32x16_bf16(afrag, bcur, zero, 0, 0, 0);
    bcur = *reinterpret_cast<const bf16x8*>(vb + (size_t)(t0 + 1) * 512);

#pragma unroll
    for (int it = 1; it < NT; ++it) {
        f32x16 c = __builtin_amdgcn_mfma_f32_32x32x16_bf16(afrag, bcur, zero, 0, 0, 0);
        if (it + 1 < NT)
            bcur = *reinterpret_cast<const bf16x8*>(vb + (size_t)(t0 + it + 1) * 512);
#pragma unroll
        for (int r = 0; r < 16; ++r) rowacc[r] += fabsf(cprev[r]);   // abs-add (free modifier)
        cprev = c;
    }
#pragma unroll
    for (int r = 0; r < 16; ++r) rowacc[r] += fabsf(cprev[r]);

    // Sum across the 32 columns held by this 32-lane group (butterfly stays in half).
#pragma unroll
    for (int off = 1; off < 32; off <<= 1) {
#pragma unroll
        for (int r = 0; r < 16; ++r) rowacc[r] += __shfl_xor(rowacc[r], off);
    }

    // C/D layout (verified m74/m101): col=lane&31, row=(reg&3)+8*(reg>>2)+4*(lane>>5)
    if (colw == 0) {
#pragma unroll
        for (int r = 0; r < 16; ++r)
            sRed[w][(r & 3) + 8 * (r >> 2) + 4 * half] = rowacc[r];
    }
    __syncthreads();

    if (threadIdx.x < 32) {
        float s = 0.0f;
#pragma unroll
        for (int ww = 0; ww < NW; ++ww) s += sRed[ww][threadIdx.x];
        // k = (1/8)|dot|, feats = mean over R, out = feats*W + b
        out[rs * 32 + threadIdx.x] = s * (Wm[0] * (1.0f / (8.0f * R_TOT))) + bias[0];
    }
}

extern "C" void kernel_launch(void* const* d_in, const int* in_sizes, int n_in,
                              void* d_out, int out_size, void* d_ws, size_t ws_size,
                              hipStream_t stream) {
    const float* x     = (const float*)d_in[0];  // (8192, 4)
    const float* x_ref = (const float*)d_in[1];  // (4096, 4)
    const float* W     = (const float*)d_in[2];  // (1, 1)
    const float* bias  = (const float*)d_in[3];  // (1,)
    float* out = (float*)d_out;                  // (8192, 1)

    ushort* U = (ushort*)d_ws;                   // [8192][16] bf16
    ushort* V = U + (size_t)B_TOT * 16;          // [4096][16] bf16

    prep_kernel<<<(B_TOT + R_TOT) * 8 / 256, 256, 0, stream>>>(x, x_ref, U, V);
    pair_mfma<<<B_TOT / 32, 512, 0, stream>>>(U, V, W, bias, out);
}

// Round 3
// 13.223 us; speedup vs baseline: 2.0006x; 1.1179x over previous
//
#include <hip/hip_runtime.h>
#include <hip/hip_bf16.h>

// out[b] = W00 * (1/R) * sum_i | prod_w cos((x[b,w]-x_ref[i,w])/2) | + b0
//
// prod_{w} cos(a_w) = (1/8) sum_{s in {+-1}^3} cos(a0 + s1 a1 + s2 a2 + s3 a3)
// cos(gx - gy) = cos gx cos gy + sin gx sin gy
// => k = (1/8) |U @ V^T| with U_row = [cos g_0..7(x), sin g_0..7(x)] (16 bf16)
// Single kernel: fragments are synthesized IN REGISTERS (native v_sin, RTN
// bf16 pack) — no prep kernel, no LDS staging. A/B use the identical
// (half,j) -> sin(g_j + half?0:pi/2) rule, so any HW k-permutation cancels.

typedef __attribute__((ext_vector_type(8)))  short bf16x8;
typedef __attribute__((ext_vector_type(16))) float f32x16;

constexpr int B_TOT = 8192;
constexpr int R_TOT = 4096;
constexpr int NTH   = 1024;                 // 16 waves/block
constexpr int NW    = NTH / 64;
constexpr int NT    = (R_TOT / 32) / NW;    // 8 col-tiles per wave

static __device__ inline ushort f2bf(float f) {
    // round-to-nearest-even f32 -> bf16 (sin/cos outputs: no NaN/Inf)
    unsigned u = __float_as_uint(f);
    return (ushort)((u + 0x7FFFu + ((u >> 16) & 1u)) >> 16);
}

// Build one 8-element fragment for `row` of src (x or x_ref).
// off = pi/2 for cos-half lanes, 0 for sin-half lanes.
static __device__ inline bf16x8 make_frag(const float4* __restrict__ src,
                                          int row, float off) {
    float4 h = src[row];
    float h0 = 0.5f * h.x, h1 = 0.5f * h.y, h2 = 0.5f * h.z, h3 = 0.5f * h.w;
    float p0 = h0 + h1, p1 = h0 - h1;
    float q0 = h2 + h3, q1 = h2 - h3;
    float g[8] = { p0 + q0, p1 + q0, p0 - q1, p1 - q1,
                   p0 + q1, p1 + q1, p0 - q0, p1 - q0 };
    bf16x8 f;
#pragma unroll
    for (int j = 0; j < 8; ++j)
        f[j] = (short)f2bf(__sinf(g[j] + off));
    return f;
}

__global__ __launch_bounds__(NTH) void pair_fused(
        const float* __restrict__ x,
        const float* __restrict__ xr,
        const float* __restrict__ Wm,
        const float* __restrict__ bias,
        float* __restrict__ out) {
    __shared__ float sRed[NW][32];
    const int l    = threadIdx.x & 63;
    const int w    = threadIdx.x >> 6;
    const int rs   = blockIdx.x;            // rows rs*32 .. rs*32+31
    const int colw = l & 31;
    const int half = l >> 5;
    const float off = half ? 0.0f : 1.5707963267948966f;  // cos = sin(g+pi/2)

    const float4* x4  = reinterpret_cast<const float4*>(x);
    const float4* xr4 = reinterpret_cast<const float4*>(xr);

    bf16x8 afrag = make_frag(x4, rs * 32 + colw, off);

    f32x16 zero, rowacc;
#pragma unroll
    for (int r = 0; r < 16; ++r) { zero[r] = 0.0f; rowacc[r] = 0.0f; }

    const int t0 = w * NT;
#pragma unroll
    for (int it = 0; it < NT; ++it) {
        bf16x8 bfrag = make_frag(xr4, (t0 + it) * 32 + colw, off);
        f32x16 c = __builtin_amdgcn_mfma_f32_32x32x16_bf16(afrag, bfrag, zero, 0, 0, 0);
#pragma unroll
        for (int r = 0; r < 16; ++r) rowacc[r] += fabsf(c[r]);
    }

    // Sum over the 32 columns held by this 32-lane group.
#pragma unroll
    for (int o = 1; o < 32; o <<= 1) {
#pragma unroll
        for (int r = 0; r < 16; ++r) rowacc[r] += __shfl_xor(rowacc[r], o);
    }

    // C/D layout (verified m74/m101): col=lane&31, row=(reg&3)+8*(reg>>2)+4*(lane>>5)
    if (colw == 0) {
#pragma unroll
        for (int r = 0; r < 16; ++r)
            sRed[w][(r & 3) + 8 * (r >> 2) + 4 * half] = rowacc[r];
    }
    __syncthreads();

    if (threadIdx.x < 32) {
        float s = 0.0f;
#pragma unroll
        for (int ww = 0; ww < NW; ++ww) s += sRed[ww][threadIdx.x];
        out[rs * 32 + threadIdx.x] = s * (Wm[0] * (1.0f / (8.0f * R_TOT))) + bias[0];
    }
}

extern "C" void kernel_launch(void* const* d_in, const int* in_sizes, int n_in,
                              void* d_out, int out_size, void* d_ws, size_t ws_size,
                              hipStream_t stream) {
    const float* x     = (const float*)d_in[0];  // (8192, 4)
    const float* x_ref = (const float*)d_in[1];  // (4096, 4)
    const float* W     = (const float*)d_in[2];  // (1, 1)
    const float* bias  = (const float*)d_in[3];  // (1,)
    float* out = (float*)d_out;                  // (8192, 1)

    pair_fused<<<B_TOT / 32, NTH, 0, stream>>>(x, x_ref, W, bias, out);
}

// Round 4
// 11.740 us; speedup vs baseline: 2.2534x; 1.1263x over previous
//
#include <hip/hip_runtime.h>
#include <hip/hip_bf16.h>

// out[b] = W00 * (1/R) * sum_i | prod_w cos((x[b,w]-x_ref[i,w])/2) | + b0
//
// prod_w cos(a_w) = (1/8) sum_{s in {+-1}^3} cos(a0 + s1 a1 + s2 a2 + s3 a3)
// cos(gx-gy) = cos gx cos gy + sin gx sin gy
// => k = (1/8)|U @ V^T|, U_row = [cos g_0..7, sin g_0..7] (16 bf16) : one
// M=8192,N=4096,K=16 bf16 MFMA GEMM, abs+mean fused. Single kernel; fragments
// synthesized in registers. Trig in REVOLUTIONS: h_w = x_w/(4*pi), cos via
// +0.25 rev folded into h0 pre-butterfly, raw v_sin_f32. bf16 pack via
// v_cvt_pk_bf16_f32 (__float22bfloat162_rn). A/B use the identical
// (half,j)->frag rule so any HW k-permutation cancels (verified R1/R2 pass).

typedef __attribute__((ext_vector_type(8)))  short bf16x8;
typedef __attribute__((ext_vector_type(16))) float f32x16;

constexpr int B_TOT = 8192;
constexpr int R_TOT = 4096;
constexpr int NTH   = 1024;                 // 16 waves/block
constexpr int NW    = NTH / 64;
constexpr int NT    = (R_TOT / 32) / NW;    // 8 col-tiles per wave

#if __has_builtin(__builtin_amdgcn_sinf)
#define SIN_REV(x) __builtin_amdgcn_sinf(x)      // sin(2*pi*x)
#else
#define SIN_REV(x) __sinf((x) * 6.283185307179586f)
#endif

static __device__ inline bf16x8 make_frag(const float4* __restrict__ src,
                                          int row, float off) {
    const float s4 = 0.07957747154594767f;  // 1/(4*pi)
    float4 h = src[row];
    float h0 = fmaf(h.x, s4, off);          // cos-half: +0.25 rev, sin-half: +0
    float h1 = h.y * s4, h2 = h.z * s4, h3 = h.w * s4;
    float p0 = h0 + h1, p1 = h0 - h1;
    float q0 = h2 + h3, q1 = h2 - h3;
    float g[8] = { p0 + q0, p1 + q0, p0 - q1, p1 - q1,
                   p0 + q1, p1 + q1, p0 - q0, p1 - q0 };
    union { bf16x8 v; __hip_bfloat162 b2[4]; } u;
#pragma unroll
    for (int k = 0; k < 4; ++k) {
        float2 p; p.x = SIN_REV(g[2 * k]); p.y = SIN_REV(g[2 * k + 1]);
        u.b2[k] = __float22bfloat162_rn(p);   // v_cvt_pk_bf16_f32
    }
    return u.v;
}

__global__ __launch_bounds__(NTH) void pair_fused(
        const float* __restrict__ x,
        const float* __restrict__ xr,
        const float* __restrict__ Wm,
        const float* __restrict__ bias,
        float* __restrict__ out) {
    __shared__ float red[32][NW][32];        // [row][wave][col] = 64 KB
    const int l    = threadIdx.x & 63;
    const int w    = threadIdx.x >> 6;
    const int rs   = blockIdx.x;             // rows rs*32 .. rs*32+31
    const int colw = l & 31;
    const int half = l >> 5;
    const float off = half ? 0.0f : 0.25f;   // cos = sin(g + 1/4 rev)

    const float4* x4  = reinterpret_cast<const float4*>(x);
    const float4* xr4 = reinterpret_cast<const float4*>(xr);

    bf16x8 afrag = make_frag(x4, rs * 32 + colw, off);

    f32x16 zero, rowacc;
#pragma unroll
    for (int r = 0; r < 16; ++r) { zero[r] = 0.0f; rowacc[r] = 0.0f; }

    const int t0 = w * NT;
#pragma unroll
    for (int it = 0; it < NT; ++it) {
        bf16x8 bfrag = make_frag(xr4, (t0 + it) * 32 + colw, off);
        f32x16 c = __builtin_amdgcn_mfma_f32_32x32x16_bf16(afrag, bfrag, zero, 0, 0, 0);
#pragma unroll
        for (int r = 0; r < 16; ++r) rowacc[r] += fabsf(c[r]);  // abs = free src-mod
    }

    // C/D layout (m74/m101): col=lane&31, row=(reg&3)+8*(reg>>2)+4*(lane>>5).
    // Dump per-wave row-partials to LDS (bank-clean: colw -> distinct banks,
    // halves 2-way = free), then cross-wave + cross-col reduce.
#pragma unroll
    for (int r = 0; r < 16; ++r)
        red[(r & 3) + 8 * (r >> 2) + 4 * half][w][colw] = rowacc[r];
    __syncthreads();

    {
        const int row = threadIdx.x >> 5;    // 0..31
        const int c   = threadIdx.x & 31;
        float s = 0.0f;
#pragma unroll
        for (int ww = 0; ww < NW; ++ww) s += red[row][ww][c];
#pragma unroll
        for (int o = 1; o < 32; o <<= 1) s += __shfl_xor(s, o);
        if (c == 0)
            out[rs * 32 + row] = s * (Wm[0] * (1.0f / (8.0f * R_TOT))) + bias[0];
    }
}

extern "C" void kernel_launch(void* const* d_in, const int* in_sizes, int n_in,
                              void* d_out, int out_size, void* d_ws, size_t ws_size,
                              hipStream_t stream) {
    const float* x     = (const float*)d_in[0];  // (8192, 4)
    const float* x_ref = (const float*)d_in[1];  // (4096, 4)
    const float* W     = (const float*)d_in[2];  // (1, 1)
    const float* bias  = (const float*)d_in[3];  // (1,)
    float* out = (float*)d_out;                  // (8192, 1)

    pair_fused<<<B_TOT / 32, NTH, 0, stream>>>(x, x_ref, W, bias, out);
}